// Round 18
// baseline (46.935 us; speedup 1.0000x reference)
//
#include <hip/hip_runtime.h>
#include <math.h>

#define NBINS 513
#define NROWS 4000
#define BATCH 8
#define FPW   8                          // output rows per chain (1 wave = 1 chain)
#define CHAINS_PER_BATCH (NROWS / FPW)   // 500

typedef const __attribute__((address_space(1))) void* gvp;
typedef __attribute__((address_space(3))) void* lvp;

__device__ __forceinline__ void cmul(float& ar, float& ai, float br, float bi) {
    const float t = ar * br - ai * bi;
    ai = ar * bi + ai * br;
    ar = t;
}

// In-place inverse DFT-8 (omega = e^{+2pi i/8}) on 8 complex register values.
__device__ __forceinline__ void idft8(float* xr, float* xi) {
    const float S = 0.70710678118654752440f;
    float er[4], ei[4], orr[4], oi[4];
    #pragma unroll
    for (int j = 0; j < 4; ++j) {
        er[j]  = xr[j] + xr[j+4];  ei[j] = xi[j] + xi[j+4];
        orr[j] = xr[j] - xr[j+4];  oi[j] = xi[j] - xi[j+4];
    }
    const float f1r = S * (orr[1] - oi[1]), f1i = S * (orr[1] + oi[1]);
    const float f2r = -oi[2],               f2i = orr[2];
    const float f3r = S * (-orr[3] - oi[3]), f3i = S * (orr[3] - oi[3]);
    {   // DFT4 (w4 = +i) over evens -> y0,y2,y4,y6
        const float eer = er[0]+er[2], eei = ei[0]+ei[2];
        const float eor = er[0]-er[2], eoi = ei[0]-ei[2];
        const float oer = er[1]+er[3], oei = ei[1]+ei[3];
        const float oor = er[1]-er[3], ooi = ei[1]-ei[3];
        xr[0] = eer + oer;  xi[0] = eei + oei;
        xr[2] = eor - ooi;  xi[2] = eoi + oor;
        xr[4] = eer - oer;  xi[4] = eei - oei;
        xr[6] = eor + ooi;  xi[6] = eoi - oor;
    }
    {   // DFT4 over odds*w8 -> y1,y3,y5,y7
        const float eer = orr[0]+f2r, eei = oi[0]+f2i;
        const float eor = orr[0]-f2r, eoi = oi[0]-f2i;
        const float oer = f1r+f3r,    oei = f1i+f3i;
        const float oor = f1r-f3r,    ooi = f1i-f3i;
        xr[1] = eer + oer;  xi[1] = eei + oei;
        xr[3] = eor - ooi;  xi[3] = eoi + oor;
        xr[5] = eer - oer;  xi[5] = eei - oei;
        xr[7] = eor + ooi;  xi[7] = eoi - oor;
    }
}

__global__ __launch_bounds__(64) void istft_kernel(
    const float* __restrict__ re, const float* __restrict__ im,
    float* __restrict__ out)
{
    __shared__ float  st[2][2][512];   // [buf][re/im][bins 1..512] — mirror source
    __shared__ float2 ex2[512];        // exchange region

    const int u  = threadIdx.x;        // 0..63
    const int b  = blockIdx.y;
    const int t0 = blockIdx.x * FPW;

    const int k1 = u >> 3;
    const int k2 = u & 7;

    // ---- per-thread twiddles (registers) ----
    const float w0 = 6.283185307179586476925f / 1024.0f;
    const float F  = 4.8828125e-4f;    // 0.5 (harness) * packed-irfft norm

    float2 twn[8];                     // F * i * w1024^(u+64j)  (pack rotation)
    #pragma unroll
    for (int j = 0; j < 8; ++j) {
        float s, c; sincosf(w0 * (float)(u + 64 * j), &s, &c);
        twn[j] = make_float2(-F * s, F * c);
    }
    float2 wA, wB0, wBs;               // stage twiddle recurrence bases
    {
        float s, c;
        sincosf(w0 * (float)(16 * k1), &s, &c);     wA  = make_float2(c, s);
        sincosf(w0 * (float)(2 * k2 * k1), &s, &c); wB0 = make_float2(c, s);
        sincosf(w0 * (float)(16 * k2), &s, &c);     wBs = make_float2(c, s);
    }

    float2 cc[4];                      // OLA carry (registers)
    #pragma unroll
    for (int m = 0; m < 4; ++m) cc[m] = make_float2(0.f, 0.f);

    const float* rebase = re + (size_t)b * NROWS * NBINS;
    const float* imbase = im + (size_t)b * NROWS * NBINS;

    // ---- async staging of bins 1..512 (the mirror set) into LDS ----
    auto stage = [&](int t, int buf) {
        const float* rp = rebase + (size_t)t * NBINS + 1;
        const float* ip = imbase + (size_t)t * NBINS + 1;
        #pragma unroll
        for (int jj = 0; jj < 8; ++jj)
            __builtin_amdgcn_global_load_lds((gvp)(rp + 64 * jj + u),
                                             (lvp)&st[buf][0][64 * jj], 4, 0, 0);
        #pragma unroll
        for (int jj = 0; jj < 8; ++jj)
            __builtin_amdgcn_global_load_lds((gvp)(ip + 64 * jj + u),
                                             (lvp)&st[buf][1][64 * jj], 4, 0, 0);
    };  // 16 vmcnt entries per frame

    // ---- straight bins X[u+64j] prefetched into registers (coalesced) ----
    float sxr[8], sxi[8];
    auto gload_straight = [&](int t) {
        if (t >= 0) {                  // t < NROWS guaranteed within a chain
            const float* rp = rebase + (size_t)t * NBINS;
            const float* ip = imbase + (size_t)t * NBINS;
            #pragma unroll
            for (int j = 0; j < 8; ++j) {
                sxr[j] = rp[u + 64 * j];
                sxi[j] = ip[u + 64 * j];
            }
        } else {
            #pragma unroll
            for (int j = 0; j < 8; ++j) { sxr[j] = 0.f; sxi[j] = 0.f; }
        }
    };  // 16 vmcnt entries per frame

    // ---- prologue: stage+load the priming frame ----
    if (t0 == 0) {
        #pragma unroll
        for (int j = 0; j < 8; ++j) { st[0][0][u + 64 * j] = 0.f; st[0][1][u + 64 * j] = 0.f; }
    } else {
        stage(t0 - 1, 0);
    }
    gload_straight(t0 - 1);
    asm volatile("s_waitcnt vmcnt(0)" ::: "memory");

    for (int it = 0; it <= FPW; ++it) {
        const int t = t0 - 1 + it;
        const int c = it & 1;

        // ---- wait for frame t's data: 32 loads (16 DMA + 16 gload) done.
        // steady-state queue = [DMA:16][gload:16][stores(t-1):4] -> vmcnt(4).
        if (it >= 2)      { asm volatile("s_waitcnt vmcnt(4)" ::: "memory"); }
        else if (it == 1) { asm volatile("s_waitcnt vmcnt(0)" ::: "memory"); }

        // ---- pack: straight from regs, mirror from LDS. z = F*e + twn*h ----
        float zr8[8], zi8[8];
        {
            const float* fr = st[c][0];   // bin p+1 at index p
            const float* fi = st[c][1];
            #pragma unroll
            for (int j = 0; j < 8; ++j) {
                const int k = u + 64 * j;
                const int pm = 511 - k;          // staged index of bin 512-k
                float xr = sxr[j], xi = sxi[j];
                float rc = fr[pm], ic = -fi[pm];
                if (k == 0) { xi = 0.f; ic = 0.f; }   // pocketfft c2r: Im ignored
                const float er0 = xr + rc, ei0 = xi + ic;
                const float hr0 = xr - rc, hi0 = xi - ic;
                zr8[j] = F * er0 + (twn[j].x * hr0 - twn[j].y * hi0);
                zi8[j] = F * ei0 + (twn[j].x * hi0 + twn[j].y * hr0);
            }
        }

        // ---- issue next frame's staging + straight loads (regs now free) ----
        if (it < FPW) { stage(t + 1, c ^ 1); gload_straight(t + 1); }

        // ---- stage A: IDFT8 over the 64s digit, twiddle w64^(k1*m0) ----
        idft8(zr8, zi8);
        {
            float tr = wA.x, ti = wA.y;
            #pragma unroll
            for (int m0 = 1; m0 < 8; ++m0) {
                cmul(zr8[m0], zi8[m0], tr, ti);
                cmul(tr, ti, wA.x, wA.y);
            }
        }
        // ---- exchange 1 (wave-internal, XOR swizzle, no barrier) ----
        #pragma unroll
        for (int m0 = 0; m0 < 8; ++m0)
            ex2[64 * m0 + 8 * ((k1 ^ m0) & 7) + k2] = make_float2(zr8[m0], zi8[m0]);
        #pragma unroll
        for (int kk = 0; kk < 8; ++kk) {
            const float2 v = ex2[64 * k1 + 8 * ((kk ^ k1) & 7) + k2];
            zr8[kk] = v.x; zi8[kk] = v.y;
        }

        // ---- stage B: IDFT8 over the 8s digit, twiddle w512^(k2*(m0B+8*m1)) ----
        idft8(zr8, zi8);
        {
            float tr = wB0.x, ti = wB0.y;
            #pragma unroll
            for (int m1 = 0; m1 < 8; ++m1) {
                cmul(zr8[m1], zi8[m1], tr, ti);
                cmul(tr, ti, wBs.x, wBs.y);
            }
        }
        // ---- exchange 2 (wave-internal) ----
        #pragma unroll
        for (int m1 = 0; m1 < 8; ++m1)
            ex2[64 * k2 + 8 * ((m1 ^ k2) & 7) + k1] = make_float2(zr8[m1], zi8[m1]);
        #pragma unroll
        for (int kk = 0; kk < 8; ++kk) {
            const float2 v = ex2[64 * kk + 8 * ((k1 ^ kk) & 7) + k2];
            zr8[kk] = v.x; zi8[kk] = v.y;
        }

        // ---- stage C: IDFT8 over the 1s digit -> z[u + 64*m2] ----
        idft8(zr8, zi8);

        // ---- overlap-add, carry in registers ----
        if (it >= 1) {
            float2* orow = (float2*)(out + ((size_t)b * NROWS + (size_t)t) * 512);
            #pragma unroll
            for (int m = 0; m < 4; ++m)
                orow[u + 64 * m] = make_float2(zr8[m] + cc[m].x, zi8[m] + cc[m].y);
        }
        #pragma unroll
        for (int m = 0; m < 4; ++m) cc[m] = make_float2(zr8[m + 4], zi8[m + 4]);
    }
}

extern "C" void kernel_launch(void* const* d_in, const int* in_sizes, int n_in,
                              void* d_out, int out_size, void* d_ws, size_t ws_size,
                              hipStream_t stream) {
    const float* re = (const float*)d_in[0];
    const float* im = (const float*)d_in[1];
    float* out = (float*)d_out;
    dim3 grid(CHAINS_PER_BATCH, BATCH);
    istft_kernel<<<grid, 64, 0, stream>>>(re, im, out);
}

// Round 19
// 46.450 us; speedup vs baseline: 1.0105x; 1.0105x over previous
//
#include <hip/hip_runtime.h>
#include <math.h>

#define NBINS 513
#define NROWS 4000
#define BATCH 8
#define FPW   8                          // output rows per chain (1 wave = 1 chain)
#define NPAIR 5                          // pairs (t0-1,t0),(t0+1,t0+2)..(t0+7,skip)
#define CHAINS_PER_BATCH (NROWS / FPW)   // 500

typedef const __attribute__((address_space(1))) void* gvp;
typedef __attribute__((address_space(3))) void* lvp;

__device__ __forceinline__ void cmul(float& ar, float& ai, float br, float bi) {
    const float t = ar * br - ai * bi;
    ai = ar * bi + ai * br;
    ar = t;
}

// In-place inverse DFT-8 (omega = e^{+2pi i/8}) on 8 complex register values.
__device__ __forceinline__ void idft8(float* xr, float* xi) {
    const float S = 0.70710678118654752440f;
    float er[4], ei[4], orr[4], oi[4];
    #pragma unroll
    for (int j = 0; j < 4; ++j) {
        er[j]  = xr[j] + xr[j+4];  ei[j] = xi[j] + xi[j+4];
        orr[j] = xr[j] - xr[j+4];  oi[j] = xi[j] - xi[j+4];
    }
    const float f1r = S * (orr[1] - oi[1]), f1i = S * (orr[1] + oi[1]);
    const float f2r = -oi[2],               f2i = orr[2];
    const float f3r = S * (-orr[3] - oi[3]), f3i = S * (orr[3] - oi[3]);
    {
        const float eer = er[0]+er[2], eei = ei[0]+ei[2];
        const float eor = er[0]-er[2], eoi = ei[0]-ei[2];
        const float oer = er[1]+er[3], oei = ei[1]+ei[3];
        const float oor = er[1]-er[3], ooi = ei[1]-ei[3];
        xr[0] = eer + oer;  xi[0] = eei + oei;
        xr[2] = eor - ooi;  xi[2] = eoi + oor;
        xr[4] = eer - oer;  xi[4] = eei - oei;
        xr[6] = eor + ooi;  xi[6] = eoi - oor;
    }
    {
        const float eer = orr[0]+f2r, eei = oi[0]+f2i;
        const float eor = orr[0]-f2r, eoi = oi[0]-f2i;
        const float oer = f1r+f3r,    oei = f1i+f3i;
        const float oor = f1r-f3r,    ooi = f1i-f3i;
        xr[1] = eer + oer;  xi[1] = eei + oei;
        xr[3] = eor - ooi;  xi[3] = eoi + oor;
        xr[5] = eer - oer;  xi[5] = eei - oei;
        xr[7] = eor + ooi;  xi[7] = eoi - oor;
    }
}

// In-place inverse DFT-16 (omega = e^{+2pi i/16}), DIT even/odd -> 2x idft8.
__device__ __forceinline__ void idft16(float* xr, float* xi) {
    float er[8], ei[8], og[8], oi[8];
    #pragma unroll
    for (int r = 0; r < 8; ++r) {
        er[r] = xr[2*r];     ei[r] = xi[2*r];
        og[r] = xr[2*r+1];   oi[r] = xi[2*r+1];
    }
    idft8(er, ei);
    idft8(og, oi);
    const float C1 = 0.92387953251128675613f;   // cos(pi/8)
    const float S1 = 0.38268343236508977173f;   // sin(pi/8)
    const float C2 = 0.70710678118654752440f;   // cos(pi/4)
    xr[0] = er[0] + og[0];  xi[0] = ei[0] + oi[0];
    xr[8] = er[0] - og[0];  xi[8] = ei[0] - oi[0];
    { const float tr = C1*og[1] - S1*oi[1], ti = C1*oi[1] + S1*og[1];
      xr[1]=er[1]+tr; xi[1]=ei[1]+ti; xr[9]=er[1]-tr;  xi[9]=ei[1]-ti; }
    { const float tr = C2*(og[2]-oi[2]),  ti = C2*(oi[2]+og[2]);
      xr[2]=er[2]+tr; xi[2]=ei[2]+ti; xr[10]=er[2]-tr; xi[10]=ei[2]-ti; }
    { const float tr = S1*og[3] - C1*oi[3], ti = S1*oi[3] + C1*og[3];
      xr[3]=er[3]+tr; xi[3]=ei[3]+ti; xr[11]=er[3]-tr; xi[11]=ei[3]-ti; }
    { const float tr = -oi[4], ti = og[4];
      xr[4]=er[4]+tr; xi[4]=ei[4]+ti; xr[12]=er[4]-tr; xi[12]=ei[4]-ti; }
    { const float tr = -S1*og[5] - C1*oi[5], ti = -S1*oi[5] + C1*og[5];
      xr[5]=er[5]+tr; xi[5]=ei[5]+ti; xr[13]=er[5]-tr; xi[13]=ei[5]-ti; }
    { const float tr = -C2*(og[6]+oi[6]), ti = C2*(og[6]-oi[6]);
      xr[6]=er[6]+tr; xi[6]=ei[6]+ti; xr[14]=er[6]-tr; xi[14]=ei[6]-ti; }
    { const float tr = -C1*og[7] - S1*oi[7], ti = -C1*oi[7] + S1*og[7];
      xr[7]=er[7]+tr; xi[7]=ei[7]+ti; xr[15]=er[7]-tr; xi[15]=ei[7]-ti; }
}

__global__ __launch_bounds__(64) void istft_kernel(
    const float* __restrict__ re, const float* __restrict__ im,
    float* __restrict__ out)
{
    // [pairbuf][row a/b][re/im][bins 0..512 (+pad)]; per-pairbuf = 8256 B.
    // The 1024-slot float2 exchange (8192 B) overlays the CONSUMED pair buffer.
    __shared__ float st[2][2][2][516];

    const int u   = threadIdx.x;       // 0..63
    const int b   = blockIdx.y;
    const int t0  = blockIdx.x * FPW;
    const int ulo = u & 7;
    const int uhi = u >> 3;

    const float w0 = 6.283185307179586476925f / 1024.0f;
    const float F  = 4.8828125e-4f;    // 0.5 (harness) * 1/1024 (irfft norm)

    float2 wU, wT2;                    // W^u ; W64^{ulo} = W^{16*ulo}
    {
        float s, c;
        sincosf(w0 * (float)u, &s, &c);          wU  = make_float2(c, s);
        sincosf(w0 * (float)(16 * ulo), &s, &c); wT2 = make_float2(c, s);
    }

    float cc[8];                       // OLA carry: Im z[n+512] per (phi,qb)
    #pragma unroll
    for (int m = 0; m < 8; ++m) cc[m] = 0.f;

    const float* rebase = re + (size_t)b * NROWS * NBINS;
    const float* imbase = im + (size_t)b * NROWS * NBINS;

    auto stageRow = [&](int t, int pb, int rs) {   // 18 vmcnt entries
        const float* rp = rebase + (size_t)t * NBINS;
        const float* ip = imbase + (size_t)t * NBINS;
        #pragma unroll
        for (int jj = 0; jj < 8; ++jj)
            __builtin_amdgcn_global_load_lds((gvp)(rp + 64 * jj + u),
                                             (lvp)&st[pb][rs][0][64 * jj], 4, 0, 0);
        __builtin_amdgcn_global_load_lds((gvp)(rp + 449 + u),
                                         (lvp)&st[pb][rs][0][449], 4, 0, 0);
        #pragma unroll
        for (int jj = 0; jj < 8; ++jj)
            __builtin_amdgcn_global_load_lds((gvp)(ip + 64 * jj + u),
                                             (lvp)&st[pb][rs][1][64 * jj], 4, 0, 0);
        __builtin_amdgcn_global_load_lds((gvp)(ip + 449 + u),
                                         (lvp)&st[pb][rs][1][449], 4, 0, 0);
    };

    // ---- prologue: pair 0 = rows (t0-1, t0) ----
    if (t0 == 0) {
        #pragma unroll
        for (int j = 0; j < 8; ++j) {
            st[0][0][0][u + 64 * j] = 0.f; st[0][0][1][u + 64 * j] = 0.f;
        }
        if (u == 0) { st[0][0][0][512] = 0.f; st[0][0][1][512] = 0.f; }
        stageRow(0, 0, 1);
    } else {
        stageRow(t0 - 1, 0, 0);
        stageRow(t0,     0, 1);
    }
    asm volatile("s_waitcnt vmcnt(0)" ::: "memory");

    for (int ip = 0; ip < NPAIR; ++ip) {
        const int a    = t0 - 1 + 2 * ip;
        const int cbuf = ip & 1;

        // queue entering pair ip>=1: [36 DMA][stores of pair ip-1]
        if (ip == 1)      { asm volatile("s_waitcnt vmcnt(8)"  ::: "memory"); }
        else if (ip >= 2) { asm volatile("s_waitcnt vmcnt(16)" ::: "memory"); }

        // ---- pack: Z[k] = X_a[k] + i X_b[k], hermitian-extended ----
        float zr[16], zi[16];
        {
            const float* ra = st[cbuf][0][0];
            const float* ia = st[cbuf][0][1];
            const float* rb = st[cbuf][1][0];
            const float* ib = st[cbuf][1][1];
            #pragma unroll
            for (int j = 0; j < 8; ++j) {          // k = u+64j <= 511
                const int k = u + 64 * j;
                float xra = ra[k], xia = ia[k], xrb = rb[k], xib = ib[k];
                if (j == 0) { if (u == 0) { xia = 0.f; xib = 0.f; } }  // bin 0
                zr[j] = xra - xib;
                zi[j] = xia + xrb;
            }
            {                                       // j = 8: k = u+512
                const int   m  = (u == 0) ? 512 : (512 - u);
                const float s0 = (u == 0) ? 0.f : 1.f;   // bin 512: Im dropped
                zr[8] = fmaf( s0, ib[m], ra[m]);
                zi[8] = fmaf(-s0, ia[m], rb[m]);
            }
            #pragma unroll
            for (int j = 9; j < 16; ++j) {          // mirror m = 1024-k in [1,448]
                const int m = 1024 - 64 * j - u;
                zr[j] =  ra[m] + ib[m];
                zi[j] = -ia[m] + rb[m];
            }
        }

        // ---- prefetch next pair's rows (clamped; garbage row is hermitian-safe) ----
        if (ip < NPAIR - 1) {
            const int na = a + 2;
            int nb_ = a + 3; if (nb_ > NROWS - 1) nb_ = NROWS - 1;
            stageRow(na,  cbuf ^ 1, 0);
            stageRow(nb_, cbuf ^ 1, 1);
        }

        // ---- stage 1: DFT-16 over j (regs) ----
        idft16(zr, zi);
        // ---- twiddle 1: F * W^{p*u}, 16-step recurrence ----
        {
            float tr = F, ti = 0.f;
            #pragma unroll
            for (int p = 0; p < 16; ++p) {
                cmul(zr[p], zi[p], tr, ti);
                cmul(tr, ti, wU.x, wU.y);
            }
        }

        // ---- exchange region overlays the consumed pair buffer ----
        float2* ex = (float2*)&st[cbuf][0][0][0];   // 1024 slots, 8192 B

        // ---- T1: regs p=(c+8phi) <-> lane k1 ----
        #pragma unroll
        for (int c = 0; c < 8; ++c)
            #pragma unroll
            for (int ph = 0; ph < 2; ++ph)
                ex[512*ph + 64*c + 8*((uhi ^ c) & 7) + ulo] =
                    make_float2(zr[c + 8*ph], zi[c + 8*ph]);
        #pragma unroll
        for (int k1 = 0; k1 < 8; ++k1)
            #pragma unroll
            for (int ph = 0; ph < 2; ++ph) {
                const float2 v = ex[512*ph + 64*uhi + 8*((k1 ^ uhi) & 7) + ulo];
                zr[k1 + 8*ph] = v.x; zi[k1 + 8*ph] = v.y;
            }

        // ---- stage 2: DFT-8 over k1 (both phi halves) ----
        idft8(zr, zi);
        idft8(zr + 8, zi + 8);
        // ---- twiddle 2: w64^{qa*k2}, k2 = ulo (applied pre-T2) ----
        {
            float tr = wT2.x, ti = wT2.y;
            #pragma unroll
            for (int qa = 1; qa < 8; ++qa) {
                cmul(zr[qa],     zi[qa],     tr, ti);
                cmul(zr[qa + 8], zi[qa + 8], tr, ti);
                cmul(tr, ti, wT2.x, wT2.y);
            }
        }
        // ---- T2: regs qa <-> lane k2 ----
        #pragma unroll
        for (int qa = 0; qa < 8; ++qa)
            #pragma unroll
            for (int ph = 0; ph < 2; ++ph)
                ex[512*ph + 64*qa + 8*((uhi ^ qa) & 7) + ulo] =
                    make_float2(zr[qa + 8*ph], zi[qa + 8*ph]);
        #pragma unroll
        for (int r = 0; r < 8; ++r)
            #pragma unroll
            for (int ph = 0; ph < 2; ++ph) {
                const float2 v = ex[512*ph + 64*uhi + 8*((ulo ^ uhi) & 7) + r];
                zr[r + 8*ph] = v.x; zi[r + 8*ph] = v.y;
            }

        // ---- stage 3: DFT-8 over k2 -> qb ----
        idft8(zr, zi);
        idft8(zr + 8, zi + 8);
        // reg (qb+8phi) = z[n], n = ulo + 8*phi + 16*uhi + 128*qb
        // Re z = x_a, Im z = x_b

        // ---- OLA + stores ----
        {
            float* rowa = out + ((size_t)b * NROWS + a) * 512;
            float* rowb = out + ((size_t)b * NROWS + a + 1) * 512;
            #pragma unroll
            for (int ph = 0; ph < 2; ++ph) {
                const int nb0 = ulo + 16 * uhi + 8 * ph;
                #pragma unroll
                for (int qb = 0; qb < 4; ++qb) {
                    const int n  = nb0 + 128 * qb;
                    const int rI = qb + 8 * ph;        // z[n]
                    const int rH = qb + 4 + 8 * ph;    // z[n+512]
                    if (ip >= 1)         rowa[n] = zr[rI] + cc[ph * 4 + qb];
                    if (ip < NPAIR - 1)  rowb[n] = zi[rI] + zr[rH];
                    cc[ph * 4 + qb] = zi[rH];
                }
            }
        }
    }
}

extern "C" void kernel_launch(void* const* d_in, const int* in_sizes, int n_in,
                              void* d_out, int out_size, void* d_ws, size_t ws_size,
                              hipStream_t stream) {
    const float* re = (const float*)d_in[0];
    const float* im = (const float*)d_in[1];
    float* out = (float*)d_out;
    dim3 grid(CHAINS_PER_BATCH, BATCH);
    istft_kernel<<<grid, 64, 0, stream>>>(re, im, out);
}